// Round 1
// baseline (1424.358 us; speedup 1.0000x reference)
//
#include <hip/hip_runtime.h>

#define NNODES 100000
#define NGRAPH 256
#define DHID 64
#define DMODEL 192
#define DFF 2048

// ---------------------------------------------------------------------------
// Edge scatter: agg[dst] += h[src].  One wave per edge, 64 lanes = 64 feats.
// ---------------------------------------------------------------------------
__global__ __launch_bounds__(256) void scatter_kernel(
    const float* __restrict__ h, const int* __restrict__ src,
    const int* __restrict__ dst, float* __restrict__ agg, int E)
{
    int lane = threadIdx.x & 63;
    int wid  = blockIdx.x * (blockDim.x >> 6) + (threadIdx.x >> 6);
    int nw   = gridDim.x * (blockDim.x >> 6);
    for (int e = wid; e < E; e += nw) {
        int s = src[e];
        int d = dst[e];
        atomicAdd(&agg[d * DHID + lane], h[s * DHID + lane]);
    }
}

// ---------------------------------------------------------------------------
// Fused GIN MLP: t = hin + agg; y = relu(bn(t@w1.T+b1)); z = relu(y@w2.T+b2)
// Then optional store of z and fused graph-pool atomicAdd.
// Wave-per-node: lane j owns output feature j.  Weights staged in LDS with
// +1 padding -> (lane+k)%32 bank pattern = 2-way conflict (free on CDNA4).
// ---------------------------------------------------------------------------
__global__ __launch_bounds__(256) void gin_mlp_kernel(
    const float* __restrict__ hin, const float* __restrict__ agg,
    const float* __restrict__ w1, const float* __restrict__ b1,
    const float* __restrict__ bng, const float* __restrict__ bnb,
    const float* __restrict__ bnm, const float* __restrict__ bnv,
    const float* __restrict__ w2, const float* __restrict__ b2,
    float* __restrict__ hout, float* __restrict__ pool,
    const int* __restrict__ batch)
{
    __shared__ float w1s[DHID][DHID + 1];
    __shared__ float w2s[DHID][DHID + 1];
    __shared__ float tbuf[4][DHID];

    int tid = threadIdx.x;
    for (int idx = tid; idx < DHID * DHID; idx += 256) {
        int j = idx >> 6, k = idx & 63;
        w1s[j][k] = w1[idx];
        w2s[j][k] = w2[idx];
    }
    __syncthreads();

    int lane = tid & 63;
    int w    = tid >> 6;

    float rs  = rsqrtf(bnv[lane] + 1e-5f);
    float sc  = bng[lane] * rs;
    float sh  = bnb[lane] - bnm[lane] * sc;
    float bb1 = b1[lane];
    float bb2 = b2[lane];

    int slot   = blockIdx.x * 4 + w;
    int stride = gridDim.x * 4;
    for (int n = slot; n < NNODES; n += stride) {
        float tv = hin[n * DHID + lane] + agg[n * DHID + lane];
        tbuf[w][lane] = tv;              // wave-private row: no barrier needed
        float y = bb1;
        #pragma unroll
        for (int k = 0; k < DHID; ++k) y += tbuf[w][k] * w1s[lane][k];
        y = fmaxf(y * sc + sh, 0.0f);
        tbuf[w][lane] = y;               // lockstep within wave: safe
        float z = bb2;
        #pragma unroll
        for (int k = 0; k < DHID; ++k) z += tbuf[w][k] * w2s[lane][k];
        z = fmaxf(z, 0.0f);
        if (hout) hout[n * DHID + lane] = z;
        atomicAdd(&pool[batch[n] * DHID + lane], z);
    }
}

// ---------------------------------------------------------------------------
// Head: per graph, seq-len-1 attention degenerates to attn = v.
// One block (192 threads) per graph.
// ---------------------------------------------------------------------------
__global__ __launch_bounds__(192) void head_kernel(
    const float* __restrict__ pools,          // [3][G][64]
    const float* __restrict__ qkv_w, const float* __restrict__ qkv_b,
    const float* __restrict__ aow,   const float* __restrict__ aob,
    const float* __restrict__ ln1g,  const float* __restrict__ ln1b,
    const float* __restrict__ ff1w,  const float* __restrict__ ff1b,
    const float* __restrict__ ff2w,  const float* __restrict__ ff2b,
    const float* __restrict__ ln2g,  const float* __restrict__ ln2b,
    const float* __restrict__ l1w,   const float* __restrict__ l1b,
    const float* __restrict__ l2w,   const float* __restrict__ l2b,
    float* __restrict__ out)
{
    __shared__ float A[DMODEL], B[DMODEL], C[DMODEL];
    __shared__ float ffb[DFF];
    __shared__ float red[DMODEL];

    int g = blockIdx.x, tid = threadIdx.x;

    // 1. load pooled features: concat(pool1, pool2, pool3)
    A[tid] = pools[(tid >> 6) * (NGRAPH * DHID) + g * DHID + (tid & 63)];
    __syncthreads();

    // 2. v = A @ qkv_w[384:576].T + qkv_b[384:]
    {
        float acc = qkv_b[384 + tid];
        const float* wr = qkv_w + (384 + tid) * DMODEL;
        for (int k = 0; k < DMODEL; ++k) acc += A[k] * wr[k];
        B[tid] = acc;
    }
    __syncthreads();

    // 3. C = A + v @ attn_out_w.T + attn_out_b
    {
        float acc = aob[tid];
        const float* wr = aow + tid * DMODEL;
        for (int k = 0; k < DMODEL; ++k) acc += B[k] * wr[k];
        C[tid] = A[tid] + acc;
    }
    __syncthreads();

    // 4. B = layernorm(C) * ln1g + ln1b   (stats computed redundantly)
    {
        float mu = 0.0f;
        for (int k = 0; k < DMODEL; ++k) mu += C[k];
        mu *= (1.0f / DMODEL);
        float var = 0.0f;
        for (int k = 0; k < DMODEL; ++k) { float d = C[k] - mu; var += d * d; }
        var *= (1.0f / DMODEL);
        float rstd = rsqrtf(var + 1e-5f);
        B[tid] = (C[tid] - mu) * rstd * ln1g[tid] + ln1b[tid];
    }
    __syncthreads();

    // 5. ffb = relu(B @ ff1_w.T + ff1_b)
    for (int o = tid; o < DFF; o += DMODEL) {
        float acc = ff1b[o];
        const float* wr = ff1w + o * DMODEL;
        for (int k = 0; k < DMODEL; ++k) acc += B[k] * wr[k];
        ffb[o] = fmaxf(acc, 0.0f);
    }
    __syncthreads();

    // 6. C = B + ffb @ ff2_w.T + ff2_b    (ff2_w rows have length DFF)
    {
        float acc = ff2b[tid];
        const float* wr = ff2w + tid * DFF;
        for (int k = 0; k < DFF; ++k) acc += ffb[k] * wr[k];
        C[tid] = B[tid] + acc;
    }
    __syncthreads();

    // 7. A = layernorm(C) * ln2g + ln2b
    {
        float mu = 0.0f;
        for (int k = 0; k < DMODEL; ++k) mu += C[k];
        mu *= (1.0f / DMODEL);
        float var = 0.0f;
        for (int k = 0; k < DMODEL; ++k) { float d = C[k] - mu; var += d * d; }
        var *= (1.0f / DMODEL);
        float rstd = rsqrtf(var + 1e-5f);
        A[tid] = (C[tid] - mu) * rstd * ln2g[tid] + ln2b[tid];
    }
    __syncthreads();

    // 8. B = relu(A @ lin1_w.T + lin1_b)
    {
        float acc = l1b[tid];
        const float* wr = l1w + tid * DMODEL;
        for (int k = 0; k < DMODEL; ++k) acc += A[k] * wr[k];
        B[tid] = fmaxf(acc, 0.0f);
    }
    __syncthreads();

    // 9. out[g] = dot(B, lin2_w) + lin2_b
    red[tid] = B[tid] * l2w[tid];
    __syncthreads();
    if (tid == 0) {
        float s = 0.0f;
        for (int k = 0; k < DMODEL; ++k) s += red[k];
        out[g] = s + l2b[0];
    }
}

extern "C" void kernel_launch(void* const* d_in, const int* in_sizes, int n_in,
                              void* d_out, int out_size, void* d_ws, size_t ws_size,
                              hipStream_t stream)
{
    const float* x    = (const float*)d_in[0];
    const int*   ei   = (const int*)d_in[1];
    const int*   bat  = (const int*)d_in[2];
    const int    E    = in_sizes[1] / 2;
    const int*   src  = ei;
    const int*   dst  = ei + E;

    // nn1 / nn2 parameter packs
    const float* nn1[8]; for (int i = 0; i < 8; ++i) nn1[i] = (const float*)d_in[3 + i];
    const float* nn2[8]; for (int i = 0; i < 8; ++i) nn2[i] = (const float*)d_in[11 + i];
    const float* qkv_w = (const float*)d_in[19];
    const float* qkv_b = (const float*)d_in[20];
    const float* aow   = (const float*)d_in[21];
    const float* aob   = (const float*)d_in[22];
    const float* ln1g  = (const float*)d_in[23];
    const float* ln1b  = (const float*)d_in[24];
    const float* ff1w  = (const float*)d_in[25];
    const float* ff1b  = (const float*)d_in[26];
    const float* ff2w  = (const float*)d_in[27];
    const float* ff2b  = (const float*)d_in[28];
    const float* ln2g  = (const float*)d_in[29];
    const float* ln2b  = (const float*)d_in[30];
    const float* l1w   = (const float*)d_in[31];
    const float* l1b   = (const float*)d_in[32];
    const float* l2w   = (const float*)d_in[33];
    const float* l2b   = (const float*)d_in[34];

    const size_t N64 = (size_t)NNODES * DHID;
    float* agg   = (float*)d_ws;
    float* h1    = agg + N64;
    float* h2    = h1 + N64;
    float* pools = h2 + N64;                 // 3 * G * 64

    hipMemsetAsync(pools, 0, 3 * NGRAPH * DHID * sizeof(float), stream);

    const int SB = 2048;   // scatter grid
    const int MB = 2048;   // mlp grid

    // ---- layer 1 (params nn1), input x -> h1, pool1
    hipMemsetAsync(agg, 0, N64 * sizeof(float), stream);
    scatter_kernel<<<SB, 256, 0, stream>>>(x, src, dst, agg, E);
    gin_mlp_kernel<<<MB, 256, 0, stream>>>(x, agg,
        nn1[0], nn1[1], nn1[2], nn1[3], nn1[4], nn1[5], nn1[6], nn1[7],
        h1, pools + 0 * NGRAPH * DHID, bat);

    // ---- layer 2 (params nn2), input h1 -> h2, pool2
    hipMemsetAsync(agg, 0, N64 * sizeof(float), stream);
    scatter_kernel<<<SB, 256, 0, stream>>>(h1, src, dst, agg, E);
    gin_mlp_kernel<<<MB, 256, 0, stream>>>(h1, agg,
        nn2[0], nn2[1], nn2[2], nn2[3], nn2[4], nn2[5], nn2[6], nn2[7],
        h2, pools + 1 * NGRAPH * DHID, bat);

    // ---- layer 3 (params nn2), input h2 -> pool3 only
    hipMemsetAsync(agg, 0, N64 * sizeof(float), stream);
    scatter_kernel<<<SB, 256, 0, stream>>>(h2, src, dst, agg, E);
    gin_mlp_kernel<<<MB, 256, 0, stream>>>(h2, agg,
        nn2[0], nn2[1], nn2[2], nn2[3], nn2[4], nn2[5], nn2[6], nn2[7],
        nullptr, pools + 2 * NGRAPH * DHID, bat);

    // ---- transformer head (attention degenerates to v), one block per graph
    head_kernel<<<NGRAPH, DMODEL, 0, stream>>>(pools,
        qkv_w, qkv_b, aow, aob, ln1g, ln1b,
        ff1w, ff1b, ff2w, ff2b, ln2g, ln2b,
        l1w, l1b, l2w, l2b, (float*)d_out);
}

// Round 2
// 719.474 us; speedup vs baseline: 1.9797x; 1.9797x over previous
//
#include <hip/hip_runtime.h>

#define NNODES 100000
#define NGRAPH 256
#define DHID 64
#define DMODEL 192
#define DFF 2048
#define SCAN_CHUNK 512
#define NCH ((NNODES + SCAN_CHUNK - 1) / SCAN_CHUNK)   // 196

// ---------------------------------------------------------------------------
// CSR construction: histogram -> scan -> counting-sort of edges by dst
// ---------------------------------------------------------------------------
__global__ __launch_bounds__(256) void hist_kernel(
    const int* __restrict__ dstv, int* __restrict__ cnt, int E)
{
    for (int e = blockIdx.x * blockDim.x + threadIdx.x; e < E;
         e += gridDim.x * blockDim.x)
        atomicAdd(&cnt[dstv[e]], 1);
}

__global__ __launch_bounds__(SCAN_CHUNK) void scan_chunk_kernel(
    const int* __restrict__ cnt, int* __restrict__ excl,
    int* __restrict__ tot, int n)
{
    __shared__ int buf[SCAN_CHUNK];
    int i = blockIdx.x * SCAN_CHUNK + threadIdx.x;
    int v = (i < n) ? cnt[i] : 0;
    buf[threadIdx.x] = v;
    __syncthreads();
    for (int off = 1; off < SCAN_CHUNK; off <<= 1) {
        int t = (threadIdx.x >= off) ? buf[threadIdx.x - off] : 0;
        __syncthreads();
        buf[threadIdx.x] += t;
        __syncthreads();
    }
    if (i < n) excl[i] = buf[threadIdx.x] - v;
    if (threadIdx.x == SCAN_CHUNK - 1) tot[blockIdx.x] = buf[threadIdx.x];
}

__global__ __launch_bounds__(256) void scan_tot_kernel(int* __restrict__ tot, int nch)
{
    __shared__ int buf[256];
    int v = (threadIdx.x < nch) ? tot[threadIdx.x] : 0;
    buf[threadIdx.x] = v;
    __syncthreads();
    for (int off = 1; off < 256; off <<= 1) {
        int t = (threadIdx.x >= off) ? buf[threadIdx.x - off] : 0;
        __syncthreads();
        buf[threadIdx.x] += t;
        __syncthreads();
    }
    if (threadIdx.x < nch) tot[threadIdx.x] = buf[threadIdx.x] - v;  // exclusive
}

__global__ __launch_bounds__(256) void finalize_rowptr_kernel(
    const int* __restrict__ excl, const int* __restrict__ tot,
    int* __restrict__ rowptr, int* __restrict__ cursor, int n, int E)
{
    for (int i = blockIdx.x * blockDim.x + threadIdx.x; i <= n;
         i += gridDim.x * blockDim.x) {
        if (i < n) {
            int v = excl[i] + tot[i / SCAN_CHUNK];
            rowptr[i] = v;
            cursor[i] = v;
        } else {
            rowptr[n] = E;
        }
    }
}

__global__ __launch_bounds__(256) void sort_edges_kernel(
    const int* __restrict__ srcv, const int* __restrict__ dstv,
    int* __restrict__ cursor, int* __restrict__ out, int E)
{
    for (int e = blockIdx.x * blockDim.x + threadIdx.x; e < E;
         e += gridDim.x * blockDim.x) {
        int p = atomicAdd(&cursor[dstv[e]], 1);
        out[p] = srcv[e];
    }
}

// ---------------------------------------------------------------------------
// Fused GIN layer: gather segment-sum + MLP + graph-pool, wave per node.
// Each wave owns a contiguous chunk of nodes (batch is sorted -> pool runs).
// ---------------------------------------------------------------------------
__global__ __launch_bounds__(256) void gin_fused_kernel(
    const float* __restrict__ hin,
    const int* __restrict__ rowptr, const int* __restrict__ srcs,
    const float* __restrict__ w1, const float* __restrict__ b1,
    const float* __restrict__ bng, const float* __restrict__ bnb,
    const float* __restrict__ bnm, const float* __restrict__ bnv,
    const float* __restrict__ w2, const float* __restrict__ b2,
    float* __restrict__ hout, float* __restrict__ pool,
    const int* __restrict__ batch)
{
    __shared__ float w1s[DHID][DHID + 1];
    __shared__ float w2s[DHID][DHID + 1];
    __shared__ float tbuf[4][DHID];

    int tid = threadIdx.x;
    for (int idx = tid; idx < DHID * DHID; idx += 256) {
        int j = idx >> 6, k = idx & 63;
        w1s[j][k] = w1[idx];
        w2s[j][k] = w2[idx];
    }
    __syncthreads();

    int lane = tid & 63;
    int w    = tid >> 6;

    float rs  = rsqrtf(bnv[lane] + 1e-5f);
    float sc  = bng[lane] * rs;
    float sh  = bnb[lane] - bnm[lane] * sc;
    float bb1 = b1[lane];
    float bb2 = b2[lane];

    int wid    = blockIdx.x * 4 + w;
    int nwaves = gridDim.x * 4;
    int per    = (NNODES + nwaves - 1) / nwaves;
    int n0     = wid * per;
    int n1     = min(n0 + per, NNODES);
    if (n0 >= n1) return;

    float poolacc = 0.0f;
    int   curg    = batch[n0];

    for (int n = n0; n < n1; ++n) {
        // ---- gather segment sum: acc = hin[n] + sum_{e->n} hin[src]
        float acc = hin[n * DHID + lane];
        int jb = rowptr[n], je = rowptr[n + 1];
        int j  = jb;
        for (; j + 3 < je; j += 4) {
            int s0 = srcs[j], s1 = srcs[j + 1], s2 = srcs[j + 2], s3 = srcs[j + 3];
            float a0 = hin[s0 * DHID + lane];
            float a1 = hin[s1 * DHID + lane];
            float a2 = hin[s2 * DHID + lane];
            float a3 = hin[s3 * DHID + lane];
            acc += (a0 + a1) + (a2 + a3);
        }
        for (; j < je; ++j) acc += hin[srcs[j] * DHID + lane];

        // ---- MLP
        tbuf[w][lane] = acc;             // wave-private row, lockstep-safe
        float y = bb1;
        #pragma unroll
        for (int k = 0; k < DHID; ++k) y += tbuf[w][k] * w1s[lane][k];
        y = fmaxf(y * sc + sh, 0.0f);
        tbuf[w][lane] = y;
        float z = bb2;
        #pragma unroll
        for (int k = 0; k < DHID; ++k) z += tbuf[w][k] * w2s[lane][k];
        z = fmaxf(z, 0.0f);

        if (hout) hout[n * DHID + lane] = z;

        // ---- pooled sum with run accumulation (batch sorted)
        int g = batch[n];
        if (g != curg) {
            atomicAdd(&pool[curg * DHID + lane], poolacc);
            poolacc = 0.0f;
            curg = g;
        }
        poolacc += z;
    }
    atomicAdd(&pool[curg * DHID + lane], poolacc);
}

// ---------------------------------------------------------------------------
// Head: seq-len-1 attention degenerates to attn = v.  One block per graph.
// ---------------------------------------------------------------------------
__global__ __launch_bounds__(192) void head_kernel(
    const float* __restrict__ pools,          // [3][G][64]
    const float* __restrict__ qkv_w, const float* __restrict__ qkv_b,
    const float* __restrict__ aow,   const float* __restrict__ aob,
    const float* __restrict__ ln1g,  const float* __restrict__ ln1b,
    const float* __restrict__ ff1w,  const float* __restrict__ ff1b,
    const float* __restrict__ ff2w,  const float* __restrict__ ff2b,
    const float* __restrict__ ln2g,  const float* __restrict__ ln2b,
    const float* __restrict__ l1w,   const float* __restrict__ l1b,
    const float* __restrict__ l2w,   const float* __restrict__ l2b,
    float* __restrict__ out)
{
    __shared__ float A[DMODEL], B[DMODEL], C[DMODEL];
    __shared__ float ffb[DFF];
    __shared__ float red[DMODEL];

    int g = blockIdx.x, tid = threadIdx.x;

    A[tid] = pools[(tid >> 6) * (NGRAPH * DHID) + g * DHID + (tid & 63)];
    __syncthreads();

    {   // v = A @ qkv_w[384:576].T + qkv_b[384:]
        float acc = qkv_b[384 + tid];
        const float* wr = qkv_w + (384 + tid) * DMODEL;
        for (int k = 0; k < DMODEL; ++k) acc += A[k] * wr[k];
        B[tid] = acc;
    }
    __syncthreads();

    {   // C = A + v @ attn_out_w.T + attn_out_b
        float acc = aob[tid];
        const float* wr = aow + tid * DMODEL;
        for (int k = 0; k < DMODEL; ++k) acc += B[k] * wr[k];
        C[tid] = A[tid] + acc;
    }
    __syncthreads();

    {   // B = layernorm(C)
        float mu = 0.0f;
        for (int k = 0; k < DMODEL; ++k) mu += C[k];
        mu *= (1.0f / DMODEL);
        float var = 0.0f;
        for (int k = 0; k < DMODEL; ++k) { float d = C[k] - mu; var += d * d; }
        var *= (1.0f / DMODEL);
        float rstd = rsqrtf(var + 1e-5f);
        B[tid] = (C[tid] - mu) * rstd * ln1g[tid] + ln1b[tid];
    }
    __syncthreads();

    for (int o = tid; o < DFF; o += DMODEL) {   // ffb = relu(B@ff1.T+b)
        float acc = ff1b[o];
        const float* wr = ff1w + o * DMODEL;
        for (int k = 0; k < DMODEL; ++k) acc += B[k] * wr[k];
        ffb[o] = fmaxf(acc, 0.0f);
    }
    __syncthreads();

    {   // C = B + ffb @ ff2.T + b
        float acc = ff2b[tid];
        const float* wr = ff2w + tid * DFF;
        for (int k = 0; k < DFF; ++k) acc += ffb[k] * wr[k];
        C[tid] = B[tid] + acc;
    }
    __syncthreads();

    {   // A = layernorm(C)
        float mu = 0.0f;
        for (int k = 0; k < DMODEL; ++k) mu += C[k];
        mu *= (1.0f / DMODEL);
        float var = 0.0f;
        for (int k = 0; k < DMODEL; ++k) { float d = C[k] - mu; var += d * d; }
        var *= (1.0f / DMODEL);
        float rstd = rsqrtf(var + 1e-5f);
        A[tid] = (C[tid] - mu) * rstd * ln2g[tid] + ln2b[tid];
    }
    __syncthreads();

    {   // B = relu(A @ lin1.T + b)
        float acc = l1b[tid];
        const float* wr = l1w + tid * DMODEL;
        for (int k = 0; k < DMODEL; ++k) acc += A[k] * wr[k];
        B[tid] = fmaxf(acc, 0.0f);
    }
    __syncthreads();

    red[tid] = B[tid] * l2w[tid];
    __syncthreads();
    if (tid == 0) {
        float s = 0.0f;
        for (int k = 0; k < DMODEL; ++k) s += red[k];
        out[g] = s + l2b[0];
    }
}

extern "C" void kernel_launch(void* const* d_in, const int* in_sizes, int n_in,
                              void* d_out, int out_size, void* d_ws, size_t ws_size,
                              hipStream_t stream)
{
    const float* x    = (const float*)d_in[0];
    const int*   ei   = (const int*)d_in[1];
    const int*   bat  = (const int*)d_in[2];
    const int    E    = in_sizes[1] / 2;
    const int*   src  = ei;
    const int*   dst  = ei + E;

    const float* nn1[8]; for (int i = 0; i < 8; ++i) nn1[i] = (const float*)d_in[3 + i];
    const float* nn2[8]; for (int i = 0; i < 8; ++i) nn2[i] = (const float*)d_in[11 + i];
    const float* qkv_w = (const float*)d_in[19];
    const float* qkv_b = (const float*)d_in[20];
    const float* aow   = (const float*)d_in[21];
    const float* aob   = (const float*)d_in[22];
    const float* ln1g  = (const float*)d_in[23];
    const float* ln1b  = (const float*)d_in[24];
    const float* ff1w  = (const float*)d_in[25];
    const float* ff1b  = (const float*)d_in[26];
    const float* ff2w  = (const float*)d_in[27];
    const float* ff2b  = (const float*)d_in[28];
    const float* ln2g  = (const float*)d_in[29];
    const float* ln2b  = (const float*)d_in[30];
    const float* l1w   = (const float*)d_in[31];
    const float* l1b   = (const float*)d_in[32];
    const float* l2w   = (const float*)d_in[33];
    const float* l2b   = (const float*)d_in[34];

    const size_t N64 = (size_t)NNODES * DHID;

    // workspace layout (floats)
    float* h1    = (float*)d_ws;
    float* h2    = h1 + N64;
    float* pools = h2 + N64;                         // 3*G*64
    int*   cnt    = (int*)(pools + 3 * NGRAPH * DHID);
    int*   excl   = cnt + NNODES;
    int*   rowptr = excl + NNODES;                   // N+1
    int*   cursor = rowptr + NNODES + 1;
    int*   tot    = cursor + NNODES;                 // NCH
    int*   srcs   = tot + NCH + 4;                   // E ints

    // ---- build CSR (counting sort by dst)
    hipMemsetAsync(cnt, 0, NNODES * sizeof(int), stream);
    hipMemsetAsync(pools, 0, 3 * NGRAPH * DHID * sizeof(float), stream);
    hist_kernel<<<1024, 256, 0, stream>>>(dst, cnt, E);
    scan_chunk_kernel<<<NCH, SCAN_CHUNK, 0, stream>>>(cnt, excl, tot, NNODES);
    scan_tot_kernel<<<1, 256, 0, stream>>>(tot, NCH);
    finalize_rowptr_kernel<<<128, 256, 0, stream>>>(excl, tot, rowptr, cursor, NNODES, E);
    sort_edges_kernel<<<1024, 256, 0, stream>>>(src, dst, cursor, srcs, E);

    const int LB = 1024;   // fused layer grid: 4096 waves, ~25 nodes each

    // ---- layer 1 (nn1): x -> h1, pool1
    gin_fused_kernel<<<LB, 256, 0, stream>>>(x, rowptr, srcs,
        nn1[0], nn1[1], nn1[2], nn1[3], nn1[4], nn1[5], nn1[6], nn1[7],
        h1, pools + 0 * NGRAPH * DHID, bat);

    // ---- layer 2 (nn2): h1 -> h2, pool2
    gin_fused_kernel<<<LB, 256, 0, stream>>>(h1, rowptr, srcs,
        nn2[0], nn2[1], nn2[2], nn2[3], nn2[4], nn2[5], nn2[6], nn2[7],
        h2, pools + 1 * NGRAPH * DHID, bat);

    // ---- layer 3 (nn2): h2 -> pool3 only
    gin_fused_kernel<<<LB, 256, 0, stream>>>(h2, rowptr, srcs,
        nn2[0], nn2[1], nn2[2], nn2[3], nn2[4], nn2[5], nn2[6], nn2[7],
        nullptr, pools + 2 * NGRAPH * DHID, bat);

    // ---- head
    head_kernel<<<NGRAPH, DMODEL, 0, stream>>>(pools,
        qkv_w, qkv_b, aow, aob, ln1g, ln1b,
        ff1w, ff1b, ff2w, ff2b, ln2g, ln2b,
        l1w, l1b, l2w, l2b, (float*)d_out);
}